// Round 1
// baseline (156.635 us; speedup 1.0000x reference)
//
#include <hip/hip_runtime.h>
#include <hip/hip_bf16.h>

// Problem constants
#define B_  8
#define TQ_ 128
#define TK_ 512
#define D_  256
#define H_  256

__device__ __forceinline__ float tanh_fast(float x) {
    // tanh(x) = 1 - 2/(1+exp(2x)); safe at +-inf (rcp(inf)=0 -> 1; exp(-inf)=0 -> -1)
    float e = __expf(x + x);
    float r = __builtin_amdgcn_rcpf(1.0f + e);
    return fmaf(-2.0f, r, 1.0f);
}

__device__ __forceinline__ float wave_red_max(float v) {
#pragma unroll
    for (int o = 32; o > 0; o >>= 1) v = fmaxf(v, __shfl_xor(v, o));
    return v;
}
__device__ __forceinline__ float wave_red_sum(float v) {
#pragma unroll
    for (int o = 32; o > 0; o >>= 1) v += __shfl_xor(v, o);
    return v;
}

// ---------------------------------------------------------------------------
// Kernel 1: projections.
//   blocks [0,64):   qp[b][q][h]   = sum_d queries[b][q][d] * Wq[d][h]   (16 q rows/block)
//   blocks [64,320): kpT[b][h][k]  = sum_d keys[b][k][d]    * Wk[d][h]   (16 k rows/block, transposed out)
// 256 threads; thread t owns h = t, 16 row accumulators.
// ---------------------------------------------------------------------------
__global__ __launch_bounds__(256) void proj_kernel(
    const float* __restrict__ queries, const float* __restrict__ keys,
    const float* __restrict__ Wq, const float* __restrict__ Wk,
    float* __restrict__ qp, float* __restrict__ kpT)
{
    __shared__ float xs[16 * 256];
    __shared__ float tile[16 * 258];   // padded stride 258 for conflict-free transpose

    const int t = threadIdx.x;
    const bool isQ = (blockIdx.x < 64);
    const float* X; const float* W; int b, r0;
    if (isQ) {
        b = blockIdx.x >> 3; r0 = (blockIdx.x & 7) * 16;
        X = queries + ((size_t)b * TQ_ + r0) * D_;  W = Wq;
    } else {
        int id = blockIdx.x - 64;
        b = id >> 5; r0 = (id & 31) * 16;
        X = keys + ((size_t)b * TK_ + r0) * D_;     W = Wk;
    }

    // stage 16 x 256 input tile (coalesced)
#pragma unroll
    for (int i = 0; i < 16; ++i) xs[i * 256 + t] = X[i * 256 + t];
    __syncthreads();

    float acc[16];
#pragma unroll
    for (int r = 0; r < 16; ++r) acc[r] = 0.0f;

    for (int d = 0; d < D_; d += 4) {
        float w0 = W[(size_t)(d + 0) * H_ + t];
        float w1 = W[(size_t)(d + 1) * H_ + t];
        float w2 = W[(size_t)(d + 2) * H_ + t];
        float w3 = W[(size_t)(d + 3) * H_ + t];
#pragma unroll
        for (int r = 0; r < 16; ++r) {
            const float4 x4 = *reinterpret_cast<const float4*>(&xs[r * 256 + d]);
            acc[r] = fmaf(x4.x, w0, acc[r]);
            acc[r] = fmaf(x4.y, w1, acc[r]);
            acc[r] = fmaf(x4.z, w2, acc[r]);
            acc[r] = fmaf(x4.w, w3, acc[r]);
        }
    }

    if (isQ) {
        float* dst = qp + ((size_t)b * TQ_ + r0) * H_ + t;
#pragma unroll
        for (int r = 0; r < 16; ++r) dst[(size_t)r * H_] = acc[r];
    } else {
        // transpose 16 rows x 256 h through LDS, write kpT[b][h][k0+r'] coalesced (64B chunks)
#pragma unroll
        for (int r = 0; r < 16; ++r) tile[r * 258 + t] = acc[r];
        __syncthreads();
        const int rp = t & 15, h0 = t >> 4;
        float* dst = kpT + (size_t)b * (H_ * TK_) + r0;
#pragma unroll
        for (int i = 0; i < 16; ++i) {
            int h = h0 + i * 16;
            dst[(size_t)h * TK_ + rp] = tile[rp * 258 + h];
        }
    }
}

// ---------------------------------------------------------------------------
// Kernel 2: fused additive-attention scores + masked softmax + PV.
// grid (32 qtiles, 8 b), 512 threads. Thread t owns k = t (one column of scores,
// 4 q rows). Then split-k PV: d = t&255, half = t>>8.
// ---------------------------------------------------------------------------
__global__ __launch_bounds__(512) void attn_kernel(
    const float* __restrict__ qp, const float* __restrict__ kpT,
    const float* __restrict__ values, const int* __restrict__ valid_lens,
    const float* __restrict__ wv, float* __restrict__ out)
{
    __shared__ float qw[H_ * 4];        // [h][q] packed (float4 per h)
    __shared__ float wvs[H_];
    __shared__ float pe[TK_ * 4];       // [k][q] unnormalized exp (float4 per k)
    __shared__ float red[8 * 4];        // per-wave partials
    __shared__ float rowm[4];
    __shared__ float rsum[4];
    __shared__ float acch[4 * 256];     // half-1 PV partials

    const int t  = threadIdx.x;
    const int b  = blockIdx.y;
    const int q0 = blockIdx.x * 4;

    // stage qp tile transposed: qw[h*4+q] = qp[b][q0+q][h]; and wv
    const float* qpb = qp + ((size_t)b * TQ_ + q0) * H_;
    for (int e = t; e < 4 * H_; e += 512) {
        int q = e >> 8, h = e & 255;
        qw[h * 4 + q] = qpb[e];
    }
    if (t < H_) wvs[t] = wv[t];
    __syncthreads();

    // ---- feature + score loop: s[q] = sum_h wv[h]*tanh(qp[q][h] + kp[k][h]) ----
    const int k = t;
    const float* kcol = kpT + (size_t)b * (H_ * TK_) + k;
    float s0 = 0.f, s1 = 0.f, s2 = 0.f, s3 = 0.f;
#pragma unroll 8
    for (int h = 0; h < H_; ++h) {
        float kk = kcol[(size_t)h * TK_];
        const float4 q4 = *reinterpret_cast<const float4*>(&qw[h * 4]);
        float w = wvs[h];
        s0 = fmaf(w, tanh_fast(q4.x + kk), s0);
        s1 = fmaf(w, tanh_fast(q4.y + kk), s1);
        s2 = fmaf(w, tanh_fast(q4.z + kk), s2);
        s3 = fmaf(w, tanh_fast(q4.w + kk), s3);
    }

    // ---- masked softmax over k (mask depends only on k and b) ----
    const int len = valid_lens[b];
    const bool valid = (k < len);
    const float NEG = -3.0e38f;
    const int wid = t >> 6, lane = t & 63;

    float m0 = wave_red_max(valid ? s0 : NEG);
    float m1 = wave_red_max(valid ? s1 : NEG);
    float m2 = wave_red_max(valid ? s2 : NEG);
    float m3 = wave_red_max(valid ? s3 : NEG);
    if (lane == 0) {
        red[wid * 4 + 0] = m0; red[wid * 4 + 1] = m1;
        red[wid * 4 + 2] = m2; red[wid * 4 + 3] = m3;
    }
    __syncthreads();
    if (t < 32) {
        int q = t >> 3, w = t & 7;
        float v = red[w * 4 + q];
#pragma unroll
        for (int o = 4; o > 0; o >>= 1) v = fmaxf(v, __shfl_xor(v, o));
        if (w == 0) rowm[q] = v;
    }
    __syncthreads();

    float e0 = valid ? __expf(s0 - rowm[0]) : 0.f;
    float e1 = valid ? __expf(s1 - rowm[1]) : 0.f;
    float e2 = valid ? __expf(s2 - rowm[2]) : 0.f;
    float e3 = valid ? __expf(s3 - rowm[3]) : 0.f;
    *reinterpret_cast<float4*>(&pe[k * 4]) = make_float4(e0, e1, e2, e3);

    float S0 = wave_red_sum(e0);
    float S1 = wave_red_sum(e1);
    float S2 = wave_red_sum(e2);
    float S3 = wave_red_sum(e3);
    if (lane == 0) {
        red[wid * 4 + 0] = S0; red[wid * 4 + 1] = S1;
        red[wid * 4 + 2] = S2; red[wid * 4 + 3] = S3;
    }
    __syncthreads();
    if (t < 32) {
        int q = t >> 3, w = t & 7;
        float v = red[w * 4 + q];
#pragma unroll
        for (int o = 4; o > 0; o >>= 1) v += __shfl_xor(v, o);
        if (w == 0) rsum[q] = 1.0f / v;   // len >= 1 so v > 0
    }
    __syncthreads();

    // ---- PV: out[q][d] = (sum_k e[q][k] * V[b][k][d]) * rsum[q]; split-k 2 halves ----
    const int d = t & 255;
    const int half = t >> 8;
    float a0 = 0.f, a1 = 0.f, a2 = 0.f, a3 = 0.f;
    const float* vb = values + (size_t)b * (TK_ * D_) + (size_t)half * 256 * D_ + d;
    const float* pb = &pe[(half * 256) * 4];
#pragma unroll 4
    for (int kk = 0; kk < 256; ++kk) {
        float v = vb[(size_t)kk * D_];
        const float4 p4 = *reinterpret_cast<const float4*>(&pb[kk * 4]);
        a0 = fmaf(p4.x, v, a0);
        a1 = fmaf(p4.y, v, a1);
        a2 = fmaf(p4.z, v, a2);
        a3 = fmaf(p4.w, v, a3);
    }
    if (half == 1) {
        acch[0 * 256 + d] = a0; acch[1 * 256 + d] = a1;
        acch[2 * 256 + d] = a2; acch[3 * 256 + d] = a3;
    }
    __syncthreads();
    if (half == 0) {
        float* ob = out + ((size_t)b * TQ_ + q0) * D_ + d;
        ob[0 * D_]  = (a0 + acch[0 * 256 + d]) * rsum[0];
        ob[1 * D_]  = (a1 + acch[1 * 256 + d]) * rsum[1];
        ob[2 * D_]  = (a2 + acch[2 * 256 + d]) * rsum[2];
        ob[3 * D_]  = (a3 + acch[3 * 256 + d]) * rsum[3];
    }
}

extern "C" void kernel_launch(void* const* d_in, const int* in_sizes, int n_in,
                              void* d_out, int out_size, void* d_ws, size_t ws_size,
                              hipStream_t stream) {
    const float* queries    = (const float*)d_in[0];
    const float* keys       = (const float*)d_in[1];
    const float* values     = (const float*)d_in[2];
    const int*   valid_lens = (const int*)  d_in[3];
    const float* Wq         = (const float*)d_in[4];
    const float* Wk         = (const float*)d_in[5];
    const float* wv         = (const float*)d_in[6];
    float* out = (float*)d_out;

    float* qp  = (float*)d_ws;                       // B*Tq*H  = 262144 f32
    float* kpT = qp + (size_t)B_ * TQ_ * H_;         // B*H*Tk  = 1048576 f32

    proj_kernel<<<320, 256, 0, stream>>>(queries, keys, Wq, Wk, qp, kpT);
    attn_kernel<<<dim3(TQ_ / 4, B_), 512, 0, stream>>>(qp, kpT, values, valid_lens, wv, out);
}

// Round 4
// 133.975 us; speedup vs baseline: 1.1691x; 1.1691x over previous
//
#include <hip/hip_runtime.h>
#include <hip/hip_bf16.h>

// Problem constants
#define B_  8
#define TQ_ 128
#define TK_ 512
#define D_  256
#define H_  256

#define KSCALE 2.8853900817779268f   // 2*log2(e): exp(2x) = exp2(KSCALE*x)

__device__ __forceinline__ float fast_exp2(float x) {
    return __builtin_amdgcn_exp2f(x);   // v_exp_f32: 2^x
}

__device__ __forceinline__ float wave_red_min(float v) {
#pragma unroll
    for (int o = 32; o > 0; o >>= 1) v = fminf(v, __shfl_xor(v, o));
    return v;
}
__device__ __forceinline__ float wave_red_sum(float v) {
#pragma unroll
    for (int o = 32; o > 0; o >>= 1) v += __shfl_xor(v, o);
    return v;
}

// ---------------------------------------------------------------------------
// Kernel 1: projections, outputs pre-scaled by KSCALE.
//   blocks [0,64):   qp[b][q][h]  = KSCALE * sum_d queries[b][q][d]*Wq[d][h]
//   blocks [64,320): kpT[b][h][k] = KSCALE * sum_d keys[b][k][d]*Wk[d][h] (transposed)
// 512 threads: h = t&255, row-half = t>>8 (8 rows each). W loads double-buffered.
// ---------------------------------------------------------------------------
__global__ __launch_bounds__(512) void proj_kernel(
    const float* __restrict__ queries, const float* __restrict__ keys,
    const float* __restrict__ Wq, const float* __restrict__ Wk,
    float* __restrict__ qp, float* __restrict__ kpT)
{
    __shared__ float xs[16 * 256];
    __shared__ float tile[16 * 258];   // padded for conflict-free transpose

    const int t  = threadIdx.x;
    const int h  = t & 255;
    const int hh = t >> 8;             // 0/1: rows 0-7 / 8-15
    const bool isQ = (blockIdx.x < 64);
    const float* X; const float* W; int b, r0;
    if (isQ) {
        b = blockIdx.x >> 3; r0 = (blockIdx.x & 7) * 16;
        X = queries + ((size_t)b * TQ_ + r0) * D_;  W = Wq;
    } else {
        int id = blockIdx.x - 64;
        b = id >> 5; r0 = (id & 31) * 16;
        X = keys + ((size_t)b * TK_ + r0) * D_;     W = Wk;
    }

    // stage 16 x 256 input tile (coalesced)
#pragma unroll
    for (int i = 0; i < 8; ++i) {
        int r = hh + i * 2;
        xs[r * 256 + h] = X[r * 256 + h];
    }
    __syncthreads();

    const float* Wcol = W + h;
    float wc[4], wn[4];
#pragma unroll
    for (int j = 0; j < 4; ++j) wc[j] = Wcol[(size_t)j * H_];

    float acc[8];
#pragma unroll
    for (int r = 0; r < 8; ++r) acc[r] = 0.0f;
    const int r0l = hh * 8;

    for (int d = 0; d < D_; d += 4) {
        const int dn = (d + 4) & (D_ - 1);   // wraps harmlessly on last iter
#pragma unroll
        for (int j = 0; j < 4; ++j) wn[j] = Wcol[(size_t)(dn + j) * H_];
#pragma unroll
        for (int r = 0; r < 8; ++r) {
            const float4 x4 = *reinterpret_cast<const float4*>(&xs[(r0l + r) * 256 + d]);
            acc[r] = fmaf(x4.x, wc[0], acc[r]);
            acc[r] = fmaf(x4.y, wc[1], acc[r]);
            acc[r] = fmaf(x4.z, wc[2], acc[r]);
            acc[r] = fmaf(x4.w, wc[3], acc[r]);
        }
#pragma unroll
        for (int j = 0; j < 4; ++j) wc[j] = wn[j];
    }
#pragma unroll
    for (int r = 0; r < 8; ++r) acc[r] *= KSCALE;

    if (isQ) {
        float* dst = qp + ((size_t)b * TQ_ + r0 + r0l) * H_ + h;
#pragma unroll
        for (int r = 0; r < 8; ++r) dst[(size_t)r * H_] = acc[r];
    } else {
        // transpose 16 rows x 256 h through LDS, write kpT coalesced
#pragma unroll
        for (int r = 0; r < 8; ++r) tile[(r0l + r) * 258 + h] = acc[r];
        __syncthreads();
        const int rp = t & 15, h0 = t >> 4;   // h0 in 0..31
        float* dst = kpT + (size_t)b * (H_ * TK_) + r0 + rp;
#pragma unroll
        for (int i = 0; i < 8; ++i) {
            int hr = h0 + i * 32;
            dst[(size_t)hr * TK_] = tile[rp * 258 + hr];
        }
    }
}

// ---------------------------------------------------------------------------
// Kernel 2: fused scores + masked softmax + PV.
// grid (32 qtiles, 8 b), 1024 threads (16 waves/CU).
// Score: k = t&511, h-half = t>>9 (128 h each), acc = sum_h wv*rcp(1+exp2(q'+k')).
// softmax(score) == softmax over k of exp2(KSCALE*(accmin - acc)).
// PV: d = t&255, k-quarter = t>>8.
// ---------------------------------------------------------------------------
__global__ __launch_bounds__(1024) void attn_kernel(
    const float* __restrict__ qp, const float* __restrict__ kpT,
    const float* __restrict__ values, const int* __restrict__ valid_lens,
    const float* __restrict__ wv, float* __restrict__ out)
{
    __shared__ float qw[H_ * 4];        // [h][q] pre-scaled q-proj
    __shared__ float wvs[H_];
    __shared__ float pacc[TK_ * 4];     // half-1 partial acc
    __shared__ float pe[TK_ * 4];       // [k][q] unnormalized probs
    __shared__ float red[8 * 4];
    __shared__ float mrow[4];           // accmin per q
    __shared__ float rs[4];             // 1/sum per q
    __shared__ float acch[12 * 256];    // PV partials for quarters 1..3

    const int t  = threadIdx.x;
    const int b  = blockIdx.y;
    const int q0 = blockIdx.x * 4;

    // stage qp tile transposed + wv (1024 threads -> one element each)
    const float* qpb = qp + ((size_t)b * TQ_ + q0) * H_;
    {
        int q = t >> 8, hx = t & 255;
        qw[hx * 4 + q] = qpb[t];
    }
    if (t < H_) wvs[t] = wv[t];
    __syncthreads();

    // ---- score loop (half of h range per thread) ----
    const int k  = t & 511;
    const int hh = t >> 9;
    const float* kcol = kpT + (size_t)b * (H_ * TK_) + (size_t)(hh * 128) * TK_ + k;
    float a0 = 0.f, a1 = 0.f, a2 = 0.f, a3 = 0.f;
#pragma unroll 4
    for (int i = 0; i < 128; ++i) {
        float kk = kcol[(size_t)i * TK_];
        const int hidx = hh * 128 + i;
        const float4 q4 = *reinterpret_cast<const float4*>(&qw[hidx * 4]);
        float w = wvs[hidx];
        float e0 = fast_exp2(q4.x + kk);
        float e1 = fast_exp2(q4.y + kk);
        float e2 = fast_exp2(q4.z + kk);
        float e3 = fast_exp2(q4.w + kk);
        a0 = fmaf(w, __builtin_amdgcn_rcpf(1.0f + e0), a0);
        a1 = fmaf(w, __builtin_amdgcn_rcpf(1.0f + e1), a1);
        a2 = fmaf(w, __builtin_amdgcn_rcpf(1.0f + e2), a2);
        a3 = fmaf(w, __builtin_amdgcn_rcpf(1.0f + e3), a3);
    }
    if (hh == 1) {
        *reinterpret_cast<float4*>(&pacc[k * 4]) = make_float4(a0, a1, a2, a3);
    }
    __syncthreads();

    const int len  = valid_lens[b];
    const int lane = t & 63, wid = t >> 6;
    const bool valid = (k < len);
    const float BIG = 3.0e38f;

    if (hh == 0) {
        const float4 p4 = *reinterpret_cast<const float4*>(&pacc[k * 4]);
        a0 += p4.x; a1 += p4.y; a2 += p4.z; a3 += p4.w;
        float m0 = wave_red_min(valid ? a0 : BIG);
        float m1 = wave_red_min(valid ? a1 : BIG);
        float m2 = wave_red_min(valid ? a2 : BIG);
        float m3 = wave_red_min(valid ? a3 : BIG);
        if (lane == 0) {
            red[wid * 4 + 0] = m0; red[wid * 4 + 1] = m1;
            red[wid * 4 + 2] = m2; red[wid * 4 + 3] = m3;
        }
    }
    __syncthreads();
    if (t < 32) {
        int q = t >> 3, w = t & 7;
        float v = red[w * 4 + q];
#pragma unroll
        for (int o = 4; o > 0; o >>= 1) v = fminf(v, __shfl_xor(v, o));
        if (w == 0) mrow[q] = v;
    }
    __syncthreads();

    if (hh == 0) {
        // p = exp2(KSCALE*(accmin - acc)), 0 for invalid k
        float e0 = valid ? fast_exp2((mrow[0] - a0) * KSCALE) : 0.f;
        float e1 = valid ? fast_exp2((mrow[1] - a1) * KSCALE) : 0.f;
        float e2 = valid ? fast_exp2((mrow[2] - a2) * KSCALE) : 0.f;
        float e3 = valid ? fast_exp2((mrow[3] - a3) * KSCALE) : 0.f;
        *reinterpret_cast<float4*>(&pe[k * 4]) = make_float4(e0, e1, e2, e3);
        float S0 = wave_red_sum(e0);
        float S1 = wave_red_sum(e1);
        float S2 = wave_red_sum(e2);
        float S3 = wave_red_sum(e3);
        if (lane == 0) {
            red[wid * 4 + 0] = S0; red[wid * 4 + 1] = S1;
            red[wid * 4 + 2] = S2; red[wid * 4 + 3] = S3;
        }
    }
    __syncthreads();
    if (t < 32) {
        int q = t >> 3, w = t & 7;
        float v = red[w * 4 + q];
#pragma unroll
        for (int o = 4; o > 0; o >>= 1) v += __shfl_xor(v, o);
        if (w == 0) rs[q] = 1.0f / v;
    }
    __syncthreads();

    // ---- PV: 4-way split-k ----
    const int d = t & 255;
    const int quar = t >> 8;
    float c0 = 0.f, c1 = 0.f, c2 = 0.f, c3 = 0.f;
    const float* vb = values + (size_t)b * (TK_ * D_) + (size_t)(quar * 128) * D_ + d;
    const float* pb = &pe[(quar * 128) * 4];
#pragma unroll 4
    for (int kk = 0; kk < 128; ++kk) {
        float v = vb[(size_t)kk * D_];
        const float4 p4 = *reinterpret_cast<const float4*>(&pb[kk * 4]);
        c0 = fmaf(p4.x, v, c0);
        c1 = fmaf(p4.y, v, c1);
        c2 = fmaf(p4.z, v, c2);
        c3 = fmaf(p4.w, v, c3);
    }
    if (quar != 0) {
        float* dstp = &acch[((quar - 1) * 4) * 256 + d];
        dstp[0]   = c0; dstp[256] = c1; dstp[512] = c2; dstp[768] = c3;
    }
    __syncthreads();
    if (quar == 0) {
        c0 += acch[(0) * 256 + d] + acch[(4) * 256 + d] + acch[(8) * 256 + d];
        c1 += acch[(1) * 256 + d] + acch[(5) * 256 + d] + acch[(9) * 256 + d];
        c2 += acch[(2) * 256 + d] + acch[(6) * 256 + d] + acch[(10) * 256 + d];
        c3 += acch[(3) * 256 + d] + acch[(7) * 256 + d] + acch[(11) * 256 + d];
        float* ob = out + ((size_t)b * TQ_ + q0) * D_ + d;
        ob[0 * D_] = c0 * rs[0];
        ob[1 * D_] = c1 * rs[1];
        ob[2 * D_] = c2 * rs[2];
        ob[3 * D_] = c3 * rs[3];
    }
}

extern "C" void kernel_launch(void* const* d_in, const int* in_sizes, int n_in,
                              void* d_out, int out_size, void* d_ws, size_t ws_size,
                              hipStream_t stream) {
    const float* queries    = (const float*)d_in[0];
    const float* keys       = (const float*)d_in[1];
    const float* values     = (const float*)d_in[2];
    const int*   valid_lens = (const int*)  d_in[3];
    const float* Wq         = (const float*)d_in[4];
    const float* Wk         = (const float*)d_in[5];
    const float* wv         = (const float*)d_in[6];
    float* out = (float*)d_out;

    float* qp  = (float*)d_ws;                       // B*Tq*H  = 262144 f32
    float* kpT = qp + (size_t)B_ * TQ_ * H_;         // B*H*Tk  = 1048576 f32

    proj_kernel<<<320, 512, 0, stream>>>(queries, keys, Wq, Wk, qp, kpT);
    attn_kernel<<<dim3(TQ_ / 4, B_), 1024, 0, stream>>>(qp, kpT, values, valid_lens, wv, out);
}